// Round 8
// baseline (861.991 us; speedup 1.0000x reference)
//
#include <hip/hip_runtime.h>

#define D 128
#define BM 64
#define NREL 8
#define KEYCAP 2048
#define SCAN_BLOCKS 782
#define MPAD (SCAN_BLOCKS * 1024)  // 800768 >= 8*N+1

typedef __attribute__((ext_vector_type(8))) short short8;
typedef __attribute__((ext_vector_type(4))) float f32x4;

typedef void __attribute__((address_space(3))) lvoid_t;

__device__ inline unsigned short f2bf(float f) {
  unsigned u = __builtin_bit_cast(unsigned, f);
  u += 0x7FFFu + ((u >> 16) & 1u);
  return (unsigned short)(u >> 16);
}

// packed 2xbf16 LDS atomic add; no memory clobber (ordering enforced by an
// explicit lgkmcnt(0)+sched_barrier before the post-gather __syncthreads).
__device__ inline void ds_pk_add(void* lptr, unsigned data) {
  asm volatile("ds_pk_add_bf16 %0, %1" ::"v"((lvoid_t*)lptr), "v"(data));
}

// emb f32 -> xb bf16, compact [N][128]
__global__ __launch_bounds__(256) void cvt_x(const float* __restrict__ x,
                                             unsigned short* __restrict__ dst,
                                             long total /* = N*32 float4 */) {
  long i = (long)blockIdx.x * 256 + threadIdx.x;
  if (i >= total) return;
  float4 v = reinterpret_cast<const float4*>(x)[i];
  unsigned lo = (unsigned)f2bf(v.x) | ((unsigned)f2bf(v.y) << 16);
  unsigned hi = (unsigned)f2bf(v.z) | ((unsigned)f2bf(v.w) << 16);
  reinterpret_cast<uint2*>(dst)[i] = make_uint2(lo, hi);
}

// Btr[layer][r][c][k] bf16: r<8 -> W[r][k][c], r=8 -> SL[k][c]
__global__ __launch_bounds__(256) void wcvt(const float* __restrict__ W1,
                                            const float* __restrict__ SL1,
                                            const float* __restrict__ W2,
                                            const float* __restrict__ SL2,
                                            unsigned short* __restrict__ Btr) {
  int idx = blockIdx.x * 256 + threadIdx.x;
  if (idx >= 2 * 9 * D * D) return;
  int l = idx >= 9 * D * D;
  int t = idx - l * 9 * D * D;
  int r = t >> 14;
  int rem = t & 16383;
  int c = rem >> 7;
  int k = rem & 127;
  const float* W = l ? W2 : W1;
  const float* SL = l ? SL2 : SL1;
  float v = (r < NREL) ? W[((r * D) + k) * D + c] : SL[k * D + c];
  Btr[idx] = f2bf(v);
}

__global__ __launch_bounds__(256) void hist_kernel(const int* __restrict__ dst,
                                                   const int* __restrict__ rel,
                                                   int* __restrict__ counts,
                                                   int E) {
  int e = blockIdx.x * 256 + threadIdx.x;
  if (e >= E) return;
  atomicAdd(&counts[(dst[e] << 3) | rel[e]], 1);
}

__global__ __launch_bounds__(256) void scan1(const int* __restrict__ in,
                                             int* __restrict__ out,
                                             int* __restrict__ bsum) {
  __shared__ int tmp[256];
  int t = threadIdx.x;
  long base = (long)blockIdx.x * 1024 + t * 4;
  int v[4];
  int s = 0;
#pragma unroll
  for (int j = 0; j < 4; ++j) {
    v[j] = in[base + j];
    s += v[j];
  }
  tmp[t] = s;
  __syncthreads();
  for (int off = 1; off < 256; off <<= 1) {
    int x = (t >= off) ? tmp[t - off] : 0;
    __syncthreads();
    tmp[t] += x;
    __syncthreads();
  }
  int run = tmp[t] - s;
  if (t == 255) bsum[blockIdx.x] = tmp[255];
#pragma unroll
  for (int j = 0; j < 4; ++j) {
    out[base + j] = run;
    run += v[j];
  }
}

__global__ __launch_bounds__(1024) void scan_top(int* __restrict__ bsum, int nb) {
  __shared__ int tmp[1024];
  int t = threadIdx.x;
  int v = (t < nb) ? bsum[t] : 0;
  tmp[t] = v;
  __syncthreads();
  for (int off = 1; off < 1024; off <<= 1) {
    int x = (t >= off) ? tmp[t - off] : 0;
    __syncthreads();
    tmp[t] += x;
    __syncthreads();
  }
  if (t < nb) bsum[t] = tmp[t] - v;
}

__global__ __launch_bounds__(256) void scan_add(int* __restrict__ starts,
                                                int* __restrict__ cursor,
                                                const int* __restrict__ bsum) {
  long base = (long)blockIdx.x * 1024 + threadIdx.x * 4;
  int add = bsum[blockIdx.x];
#pragma unroll
  for (int j = 0; j < 4; ++j) {
    int v = starts[base + j] + add;
    starts[base + j] = v;
    cursor[base + j] = v;
  }
}

__global__ __launch_bounds__(256) void reorder(const int* __restrict__ src,
                                               const int* __restrict__ dst,
                                               const int* __restrict__ rel,
                                               int* __restrict__ cursor,
                                               int2* __restrict__ es, int E) {
  int e = blockIdx.x * 256 + threadIdx.x;
  if (e >= E) return;
  int key = (dst[e] << 3) | rel[e];
  int pos = atomicAdd(&cursor[key], 1);
  es[pos] = make_int2(src[e], key);
}

// Fused RGCN layer, BM=64 rows/block, full K=128 single gather pass.
// LDS: 8 relation tiles [64][128] bf16 (16KB each, XOR-swizzled) + key buffer.
// Gather: stage edge keys to LDS (coalesced), then 2-deep pipelined x-row
// loads (4 lanes/edge x 64B) accumulated via ds_pk_add. MFMA: 9 phases
// (r=0..7 from LDS tiles, r=8 self-loop from global; B from L2-resident Btr).
__global__ __launch_bounds__(256, 1) void fused_layer(
    const unsigned short* __restrict__ xb, const int* __restrict__ starts,
    const int2* __restrict__ es, const unsigned short* __restrict__ Btr,
    const float* __restrict__ bias, unsigned short* __restrict__ xout_b,
    float* __restrict__ outf, int N) {
  extern __shared__ char lds[];
  char* tiles = lds;                                // 8 x 16384 = 131072 B
  int2* kbuf = reinterpret_cast<int2*>(lds + 131072);  // KEYCAP x 8 B

  const int tid = threadIdx.x;
  const int wave = tid >> 6, lane = tid & 63;
  const int wm = wave >> 1, wn = wave & 1;
  const int l15 = lane & 15, lq = lane >> 4;
  const int row0 = blockIdx.x * BM;
  const int rowend = (row0 + BM < N) ? (row0 + BM) : N;
  const int eg = lane >> 2, cb = lane & 3;
  const char* xbB = reinterpret_cast<const char*>(xb);
  const char* BtrB = reinterpret_cast<const char*>(Btr);

  const int e0 = starts[row0 << 3];
  const int e1 = starts[rowend << 3];

  f32x4 acc[2][4];
#pragma unroll
  for (int m = 0; m < 2; ++m)
#pragma unroll
    for (int n = 0; n < 4; ++n)
#pragma unroll
      for (int q = 0; q < 4; ++q) acc[m][n][q] = 0.f;

  // zero all 8 tiles (128 KB)
#pragma unroll
  for (int i = 0; i < 32; ++i)
    *reinterpret_cast<int4*>(tiles + i * 4096 + tid * 16) =
        make_int4(0, 0, 0, 0);

  for (int ec = e0; ec < e1; ec += KEYCAP) {
    const int cnt = ((e1 - ec) < KEYCAP) ? (e1 - ec) : KEYCAP;
    __syncthreads();  // tiles zeroed (iter 0) / prev-chunk kbuf reads done
    for (int i = tid; i < cnt; i += 256) kbuf[i] = es[ec + i];
    __syncthreads();

    const int gcnt = (cnt + 15) >> 4;  // 16 edges per group
    int g = wave;
    // prologue: fetch group g
    int idx0 = g * 16 + eg;
    bool v0 = idx0 < cnt;
    int2 k0 = kbuf[v0 ? idx0 : 0];
    int s0 = v0 ? k0.x : 0;
    const char* xp0 = xbB + (size_t)s0 * 256 + cb * 16;
    uint4 a0 = *reinterpret_cast<const uint4*>(xp0);
    uint4 b0 = *reinterpret_cast<const uint4*>(xp0 + 64);
    uint4 c0 = *reinterpret_cast<const uint4*>(xp0 + 128);
    uint4 d0 = *reinterpret_cast<const uint4*>(xp0 + 192);
    while (g < gcnt) {
      const int gn = g + 4;
      // prefetch next group (independent of the DS ops below)
      int idx1 = gn * 16 + eg;
      bool v1 = idx1 < cnt;
      int2 k1 = kbuf[v1 ? idx1 : 0];
      int s1 = v1 ? k1.x : 0;
      const char* xp1 = xbB + (size_t)s1 * 256 + cb * 16;
      uint4 a1 = *reinterpret_cast<const uint4*>(xp1);
      uint4 b1 = *reinterpret_cast<const uint4*>(xp1 + 64);
      uint4 c1 = *reinterpret_cast<const uint4*>(xp1 + 128);
      uint4 d1 = *reinterpret_cast<const uint4*>(xp1 + 192);
      // consume current
      if (v0) {
        const int dstl = (k0.y >> 3) - row0;
        char* base = tiles + (k0.y & 7) * 16384 + dstl * 256;
        const int sw = (dstl & 7) << 4;
        char* p0 = base + ((cb * 16) ^ sw);
        char* p1 = base + ((64 + cb * 16) ^ sw);
        char* p2 = base + ((128 + cb * 16) ^ sw);
        char* p3 = base + ((192 + cb * 16) ^ sw);
        ds_pk_add(p0 + 0, a0.x); ds_pk_add(p0 + 4, a0.y);
        ds_pk_add(p0 + 8, a0.z); ds_pk_add(p0 + 12, a0.w);
        ds_pk_add(p1 + 0, b0.x); ds_pk_add(p1 + 4, b0.y);
        ds_pk_add(p1 + 8, b0.z); ds_pk_add(p1 + 12, b0.w);
        ds_pk_add(p2 + 0, c0.x); ds_pk_add(p2 + 4, c0.y);
        ds_pk_add(p2 + 8, c0.z); ds_pk_add(p2 + 12, c0.w);
        ds_pk_add(p3 + 0, d0.x); ds_pk_add(p3 + 4, d0.y);
        ds_pk_add(p3 + 8, d0.z); ds_pk_add(p3 + 12, d0.w);
      }
      k0 = k1; v0 = v1;
      a0 = a1; b0 = b1; c0 = c1; d0 = d1;
      g = gn;
    }
  }
  // drain the (compiler-invisible) DS atomics before the barrier
  asm volatile("s_waitcnt lgkmcnt(0)");
  __builtin_amdgcn_sched_barrier(0);
  __syncthreads();

  // 9 MFMA phases over K=128
  for (int r = 0; r < 9; ++r) {
    short8 af[2][4], bfr[4][4];
#pragma unroll
    for (int n = 0; n < 4; ++n) {
      int cc = wn * 64 + n * 16 + l15;
#pragma unroll
      for (int kq = 0; kq < 4; ++kq)
        bfr[n][kq] = *reinterpret_cast<const short8*>(
            BtrB + (((size_t)r * D + cc) * D + kq * 32 + lq * 8) * 2);
    }
    if (r < NREL) {
      const char* tb = tiles + r * 16384;
#pragma unroll
      for (int m = 0; m < 2; ++m) {
        int rr = wm * 32 + m * 16 + l15;
        int sw = (rr & 7) << 4;
#pragma unroll
        for (int kq = 0; kq < 4; ++kq)
          af[m][kq] = *reinterpret_cast<const short8*>(
              tb + rr * 256 + ((kq * 64 + lq * 16) ^ sw));
      }
    } else {
#pragma unroll
      for (int m = 0; m < 2; ++m) {
        int grow = row0 + wm * 32 + m * 16 + l15;
        if (grow >= N) grow = N - 1;
#pragma unroll
        for (int kq = 0; kq < 4; ++kq)
          af[m][kq] = *reinterpret_cast<const short8*>(
              xbB + (size_t)grow * 256 + kq * 64 + lq * 16);
      }
    }
#pragma unroll
    for (int m = 0; m < 2; ++m)
#pragma unroll
      for (int n = 0; n < 4; ++n)
#pragma unroll
        for (int kq = 0; kq < 4; ++kq)
          acc[m][n] = __builtin_amdgcn_mfma_f32_16x16x32_bf16(
              af[m][kq], bfr[n][kq], acc[m][n], 0, 0, 0);
  }

  // epilogue: C/D layout col = lane&15, row = (lane>>4)*4 + reg
#pragma unroll
  for (int n = 0; n < 4; ++n) {
    int col = wn * 64 + n * 16 + l15;
    float bv = bias[col];
#pragma unroll
    for (int m = 0; m < 2; ++m) {
      int rbase = row0 + wm * 32 + m * 16 + lq * 4;
#pragma unroll
      for (int q = 0; q < 4; ++q) {
        int row = rbase + q;
        if (row < N) {
          float v = fmaxf(acc[m][n][q] + bv, 0.f);
          if (outf)
            outf[(size_t)row * D + col] = v;
          else
            xout_b[(size_t)row * D + col] = f2bf(v);
        }
      }
    }
  }
}

extern "C" void kernel_launch(void* const* d_in, const int* in_sizes, int n_in,
                              void* d_out, int out_size, void* d_ws, size_t ws_size,
                              hipStream_t stream) {
  const float* emb = (const float*)d_in[0];
  const float* W1 = (const float*)d_in[1];
  const float* SL1 = (const float*)d_in[2];
  const float* B1 = (const float*)d_in[3];
  const float* W2 = (const float*)d_in[4];
  const float* SL2 = (const float*)d_in[5];
  const float* B2 = (const float*)d_in[6];
  const int* eidx = (const int*)d_in[7];
  const int* etyp = (const int*)d_in[8];
  const int N = in_sizes[0] / D;
  const int E = in_sizes[8];
  const int* srcp = eidx;
  const int* dstp = eidx + E;
  float* outp = (float*)d_out;

  char* w = (char*)d_ws;
  unsigned short* xb0 = (unsigned short*)w;            // N*128 bf16
  unsigned short* xb1 = xb0 + (size_t)N * D;           // N*128 bf16
  unsigned short* Btr = xb1 + (size_t)N * D;           // 2*9*128*128 bf16
  int* counts = (int*)(Btr + 2 * 9 * D * D);           // MPAD ints
  int* starts = counts + MPAD;
  int* cursor = starts + MPAD;
  int* bsum = cursor + MPAD;                           // 1024 ints
  int2* es = (int2*)(bsum + 1024);                     // E int2 (src, key)

  const int eb = (E + 255) / 256;
  const int gm_blocks = (N + BM - 1) / BM;
  const int LDS_BYTES = 131072 + KEYCAP * 8;  // 147456

  hipFuncSetAttribute(reinterpret_cast<const void*>(fused_layer),
                      hipFuncAttributeMaxDynamicSharedMemorySize, LDS_BYTES);

  // preprocessing (graph structure shared by both layers)
  hipMemsetAsync(counts, 0, (size_t)MPAD * 4, stream);
  cvt_x<<<(int)(((long)N * 32 + 255) / 256), 256, 0, stream>>>(emb, xb0,
                                                               (long)N * 32);
  wcvt<<<(2 * 9 * D * D + 255) / 256, 256, 0, stream>>>(W1, SL1, W2, SL2, Btr);
  hist_kernel<<<eb, 256, 0, stream>>>(dstp, etyp, counts, E);
  scan1<<<SCAN_BLOCKS, 256, 0, stream>>>(counts, starts, bsum);
  scan_top<<<1, 1024, 0, stream>>>(bsum, SCAN_BLOCKS);
  scan_add<<<SCAN_BLOCKS, 256, 0, stream>>>(starts, cursor, bsum);
  reorder<<<eb, 256, 0, stream>>>(srcp, dstp, etyp, cursor, es, E);

  // layer 1: xb0 -> xb1 (bf16); layer 2: xb1 -> outp (f32)
  fused_layer<<<gm_blocks, 256, LDS_BYTES, stream>>>(xb0, starts, es, Btr, B1,
                                                     xb1, nullptr, N);
  fused_layer<<<gm_blocks, 256, LDS_BYTES, stream>>>(
      xb1, starts, es, Btr + 9 * D * D, B2, nullptr, outp, N);
}

// Round 10
// 552.014 us; speedup vs baseline: 1.5615x; 1.5615x over previous
//
#include <hip/hip_runtime.h>

#define D 128
#define NREL 8
#define RC0 5  // chunk 0: rels 0..4
#define RC1 4  // chunk 1: rels 5..7 + self-loop(8)

typedef __attribute__((ext_vector_type(8))) short short8;
typedef __attribute__((ext_vector_type(4))) float f32x4;

__device__ inline unsigned short f2bf(float f) {
  unsigned u = __builtin_bit_cast(unsigned, f);
  u += 0x7FFFu + ((u >> 16) & 1u);
  return (unsigned short)(u >> 16);
}

__device__ inline unsigned cvt_pk_bf16(float lo, float hi) {
  unsigned r;
  asm("v_cvt_pk_bf16_f32 %0, %1, %2" : "=v"(r) : "v"(lo), "v"(hi));
  return r;
}

// emb f32 -> xb bf16, compact [N][128]
__global__ __launch_bounds__(256) void cvt_x(const float* __restrict__ x,
                                             unsigned short* __restrict__ dst,
                                             long total /* = N*32 float4 */) {
  long i = (long)blockIdx.x * 256 + threadIdx.x;
  if (i >= total) return;
  float4 v = reinterpret_cast<const float4*>(x)[i];
  unsigned lo = (unsigned)f2bf(v.x) | ((unsigned)f2bf(v.y) << 16);
  unsigned hi = (unsigned)f2bf(v.z) | ((unsigned)f2bf(v.w) << 16);
  reinterpret_cast<uint2*>(dst)[i] = make_uint2(lo, hi);
}

// Btr[layer][r][c][k] bf16: r<8 -> W[r][k][c], r=8 -> SL[k][c]
__global__ __launch_bounds__(256) void wcvt(const float* __restrict__ W1,
                                            const float* __restrict__ SL1,
                                            const float* __restrict__ W2,
                                            const float* __restrict__ SL2,
                                            unsigned short* __restrict__ Btr) {
  int idx = blockIdx.x * 256 + threadIdx.x;
  if (idx >= 2 * 9 * D * D) return;
  int l = idx >= 9 * D * D;
  int t = idx - l * 9 * D * D;
  int r = t >> 14;
  int rem = t & 16383;
  int c = rem >> 7;
  int k = rem & 127;
  const float* W = l ? W2 : W1;
  const float* SL = l ? SL2 : SL1;
  float v = (r < NREL) ? W[((r * D) + k) * D + c] : SL[k * D + c];
  Btr[idx] = f2bf(v);
}

__global__ __launch_bounds__(256) void hist_kernel(const int* __restrict__ dst,
                                                   int* __restrict__ counts,
                                                   int E) {
  int e = blockIdx.x * 256 + threadIdx.x;
  if (e >= E) return;
  atomicAdd(&counts[dst[e]], 1);
}

__global__ __launch_bounds__(256) void scan1(const int* __restrict__ in,
                                             int* __restrict__ out,
                                             int* __restrict__ bsum) {
  __shared__ int tmp[256];
  int t = threadIdx.x;
  long base = (long)blockIdx.x * 1024 + t * 4;
  int v[4];
  int s = 0;
#pragma unroll
  for (int j = 0; j < 4; ++j) {
    v[j] = in[base + j];
    s += v[j];
  }
  tmp[t] = s;
  __syncthreads();
  for (int off = 1; off < 256; off <<= 1) {
    int x = (t >= off) ? tmp[t - off] : 0;
    __syncthreads();
    tmp[t] += x;
    __syncthreads();
  }
  int run = tmp[t] - s;
  if (t == 255) bsum[blockIdx.x] = tmp[255];
#pragma unroll
  for (int j = 0; j < 4; ++j) {
    out[base + j] = run;
    run += v[j];
  }
}

__global__ __launch_bounds__(1024) void scan_top(int* __restrict__ bsum, int nb) {
  __shared__ int tmp[1024];
  int t = threadIdx.x;
  int v = (t < nb) ? bsum[t] : 0;
  tmp[t] = v;
  __syncthreads();
  for (int off = 1; off < 1024; off <<= 1) {
    int x = (t >= off) ? tmp[t - off] : 0;
    __syncthreads();
    tmp[t] += x;
    __syncthreads();
  }
  if (t < nb) bsum[t] = tmp[t] - v;
}

__global__ __launch_bounds__(256) void scan_add(int* __restrict__ starts,
                                                int* __restrict__ cursor,
                                                const int* __restrict__ bsum) {
  long base = (long)blockIdx.x * 1024 + threadIdx.x * 4;
  int add = bsum[blockIdx.x];
#pragma unroll
  for (int j = 0; j < 4; ++j) {
    int v = starts[base + j] + add;
    starts[base + j] = v;
    cursor[base + j] = v;
  }
}

// esz[pos] = rel*N + src : Z-row index of the message, sorted by dst
__global__ __launch_bounds__(256) void reorder(const int* __restrict__ src,
                                               const int* __restrict__ dst,
                                               const int* __restrict__ rel,
                                               int* __restrict__ cursor,
                                               int* __restrict__ esz, int E,
                                               int N) {
  int e = blockIdx.x * 256 + threadIdx.x;
  if (e >= E) return;
  int pos = atomicAdd(&cursor[dst[e]], 1);
  esz[pos] = rel[e] * N + src[e];
}

// Z[r][n] = x[n] @ W[r0+r] for r=0..rc-1. Pure-register MFMA, no LDS/barriers.
// Z slot j of a row packs bf16 cols (j, j+64) via v_cvt_pk_bf16_f32.
__global__ __launch_bounds__(256) void zgemm(
    const unsigned short* __restrict__ xb,
    const unsigned short* __restrict__ Btr /* chunk base */,
    unsigned* __restrict__ Z2, int N, int rc) {
  const int lane = threadIdx.x & 63;
  const int wave = threadIdx.x >> 6;
  const int l15 = lane & 15, lq = lane >> 4;
  const int wrow = (blockIdx.x * 4 + wave) * 32;
  if (wrow >= N) return;

  short8 af[2][4];
#pragma unroll
  for (int m = 0; m < 2; ++m) {
    int grow = wrow + m * 16 + l15;
    if (grow >= N) grow = N - 1;
#pragma unroll
    for (int kq = 0; kq < 4; ++kq)
      af[m][kq] = *reinterpret_cast<const short8*>(xb + (size_t)grow * D +
                                                   kq * 32 + lq * 8);
  }

  for (int r = 0; r < rc; ++r) {
#pragma unroll
    for (int np = 0; np < 4; ++np) {
      const int cA = np * 16 + l15;
      short8 ba[4], bb[4];
#pragma unroll
      for (int kq = 0; kq < 4; ++kq) {
        ba[kq] = *reinterpret_cast<const short8*>(
            Btr + ((size_t)r * D + cA) * D + kq * 32 + lq * 8);
        bb[kq] = *reinterpret_cast<const short8*>(
            Btr + ((size_t)r * D + cA + 64) * D + kq * 32 + lq * 8);
      }
      f32x4 accA[2], accB[2];
#pragma unroll
      for (int m = 0; m < 2; ++m)
#pragma unroll
        for (int q = 0; q < 4; ++q) {
          accA[m][q] = 0.f;
          accB[m][q] = 0.f;
        }
#pragma unroll
      for (int m = 0; m < 2; ++m)
#pragma unroll
        for (int kq = 0; kq < 4; ++kq) {
          accA[m] = __builtin_amdgcn_mfma_f32_16x16x32_bf16(af[m][kq], ba[kq],
                                                            accA[m], 0, 0, 0);
          accB[m] = __builtin_amdgcn_mfma_f32_16x16x32_bf16(af[m][kq], bb[kq],
                                                            accB[m], 0, 0, 0);
        }
      // C layout col=l15, row=lq*4+q. Slot j = np*16+l15 packs cols (j, j+64).
#pragma unroll
      for (int m = 0; m < 2; ++m)
#pragma unroll
        for (int q = 0; q < 4; ++q) {
          int grow = wrow + m * 16 + lq * 4 + q;
          if (grow < N) {
            unsigned pk = cvt_pk_bf16(accA[m][q], accB[m][q]);
            Z2[((size_t)r * N + grow) * 64 + np * 16 + l15] = pk;
          }
        }
    }
  }
}

// Segment-sum over the dst-sorted edge list, relation-chunked.
// Pass 0 (final=0): agg[row] = sum of Z rows with rel in [lo,hi).
// Pass 1 (final=1): out = relu(agg + sum rels [lo,hi) + Z[selfOff*N+row] + bias).
// One wave per row; lane j handles packed cols (j, j+64). 8-edge batches of
// independent clamped gathers (mask is wave-uniform; clamped idx is L1-hot).
__global__ __launch_bounds__(256) void segsum(
    const unsigned* __restrict__ Z2, const int* __restrict__ esz,
    const int* __restrict__ starts, const float* __restrict__ bias,
    float* __restrict__ agg, unsigned short* __restrict__ xout_b,
    float* __restrict__ outf, int N, int lo, int hi, int selfOff, int final) {
  int row = blockIdx.x * 4 + (threadIdx.x >> 6);
  if (row >= N) return;
  int lane = threadIdx.x & 63;
  int s0 = starts[row], s1 = starts[row + 1];
  const int zlo = lo * N, zhi = hi * N;
  float a0 = 0.f, a1 = 0.f;
  for (int base = s0; base < s1; base += 8) {
    int zr[8];
    bool ok[8];
#pragma unroll
    for (int j = 0; j < 8; ++j) {
      int e = base + j;
      int z = (e < s1) ? esz[e] : -1;
      ok[j] = (z >= zlo) & (z < zhi);
      zr[j] = ok[j] ? (z - zlo) : 0;
    }
    unsigned v[8];
#pragma unroll
    for (int j = 0; j < 8; ++j) v[j] = Z2[(size_t)zr[j] * 64 + lane];
#pragma unroll
    for (int j = 0; j < 8; ++j)
      if (ok[j]) {
        a0 += __builtin_bit_cast(float, v[j] << 16);
        a1 += __builtin_bit_cast(float, v[j] & 0xffff0000u);
      }
  }
  if (final) {
    {  // self-loop row
      unsigned v = Z2[((size_t)selfOff * N + row) * 64 + lane];
      a0 += __builtin_bit_cast(float, v << 16);
      a1 += __builtin_bit_cast(float, v & 0xffff0000u);
    }
    a0 += agg[(size_t)row * D + lane];
    a1 += agg[(size_t)row * D + lane + 64];
    a0 = fmaxf(a0 + bias[lane], 0.f);
    a1 = fmaxf(a1 + bias[lane + 64], 0.f);
    if (outf) {
      outf[(size_t)row * D + lane] = a0;
      outf[(size_t)row * D + lane + 64] = a1;
    } else {
      xout_b[(size_t)row * D + lane] = f2bf(a0);
      xout_b[(size_t)row * D + lane + 64] = f2bf(a1);
    }
  } else {
    agg[(size_t)row * D + lane] = a0;
    agg[(size_t)row * D + lane + 64] = a1;
  }
}

extern "C" void kernel_launch(void* const* d_in, const int* in_sizes, int n_in,
                              void* d_out, int out_size, void* d_ws, size_t ws_size,
                              hipStream_t stream) {
  const float* emb = (const float*)d_in[0];
  const float* W1 = (const float*)d_in[1];
  const float* SL1 = (const float*)d_in[2];
  const float* B1 = (const float*)d_in[3];
  const float* W2 = (const float*)d_in[4];
  const float* SL2 = (const float*)d_in[5];
  const float* B2 = (const float*)d_in[6];
  const int* eidx = (const int*)d_in[7];
  const int* etyp = (const int*)d_in[8];
  const int N = in_sizes[0] / D;
  const int E = in_sizes[8];
  const int* srcp = eidx;
  const int* dstp = eidx + E;
  float* outp = (float*)d_out;

  const int nb = (N + 1 + 1023) >> 10;
  const size_t npad = (size_t)nb << 10;

  // workspace layout (~209 MB; proven-safe bound ~231 MB from round 2)
  char* w = (char*)d_ws;
  unsigned* Z2 = (unsigned*)w;                           // RC0*N*64 u32 (128 MB)
  float* agg = (float*)(Z2 + (size_t)RC0 * N * 64);      // N*128 f32 (51.2 MB)
  unsigned short* xb = (unsigned short*)(agg + (size_t)N * D);  // N*128 bf16
  unsigned short* Btr = xb + (size_t)N * D;              // 2*9*128*128 bf16
  int* counts = (int*)(Btr + 2 * 9 * D * D);             // npad ints
  int* starts = counts + npad;
  int* cursor = starts + npad;
  int* bsum = cursor + npad;                             // 1024 ints
  int* esz = bsum + 1024;                                // E ints

  const int eb = (E + 255) / 256;
  const int zg_blocks = (N + 127) / 128;  // 4 waves x 32 rows
  const int ss_blocks = (N + 3) / 4;

  // preprocessing (graph structure shared by both layers)
  hipMemsetAsync(counts, 0, npad * 4, stream);
  cvt_x<<<(int)(((long)N * 32 + 255) / 256), 256, 0, stream>>>(emb, xb,
                                                               (long)N * 32);
  wcvt<<<(2 * 9 * D * D + 255) / 256, 256, 0, stream>>>(W1, SL1, W2, SL2, Btr);
  hist_kernel<<<eb, 256, 0, stream>>>(dstp, counts, E);
  scan1<<<nb, 256, 0, stream>>>(counts, starts, bsum);
  scan_top<<<1, 1024, 0, stream>>>(bsum, nb);
  scan_add<<<nb, 256, 0, stream>>>(starts, cursor, bsum);
  reorder<<<eb, 256, 0, stream>>>(srcp, dstp, etyp, cursor, esz, E, N);

  auto layer = [&](const unsigned short* Bt, const float* bias,
                   unsigned short* ob, float* of) {
    // chunk 0: rels 0..4 -> agg
    zgemm<<<zg_blocks, 256, 0, stream>>>(xb, Bt, Z2, N, RC0);
    segsum<<<ss_blocks, 256, 0, stream>>>(Z2, esz, starts, bias, agg, nullptr,
                                          nullptr, N, 0, RC0, 0, 0);
    // chunk 1: rels 5..7 + self-loop(8) -> finalize
    zgemm<<<zg_blocks, 256, 0, stream>>>(xb, Bt + (size_t)RC0 * D * D, Z2, N,
                                         RC1);
    segsum<<<ss_blocks, 256, 0, stream>>>(Z2, esz, starts, bias, agg, ob, of,
                                          N, RC0, NREL, NREL - RC0, 1);
  };

  layer(Btr, B1, xb, nullptr);                 // layer 1: xb -> xb (bf16)
  layer(Btr + 9 * D * D, B2, nullptr, outp);   // layer 2: xb -> outp (f32)
}

// Round 11
// 549.820 us; speedup vs baseline: 1.5678x; 1.0040x over previous
//
#include <hip/hip_runtime.h>

#define D 128
#define NREL 8
#define RC0 5  // chunk 0: rels 0..4
#define RC1 4  // chunk 1: rels 5..7 + self-loop(8)

typedef __attribute__((ext_vector_type(8))) short short8;
typedef __attribute__((ext_vector_type(4))) float f32x4;

__device__ inline unsigned short f2bf(float f) {
  unsigned u = __builtin_bit_cast(unsigned, f);
  u += 0x7FFFu + ((u >> 16) & 1u);
  return (unsigned short)(u >> 16);
}

__device__ inline unsigned cvt_pk_bf16(float lo, float hi) {
  unsigned r;
  asm("v_cvt_pk_bf16_f32 %0, %1, %2" : "=v"(r) : "v"(lo), "v"(hi));
  return r;
}

// emb f32 -> xb bf16, compact [N][128]
__global__ __launch_bounds__(256) void cvt_x(const float* __restrict__ x,
                                             unsigned short* __restrict__ dst,
                                             long total /* = N*32 float4 */) {
  long i = (long)blockIdx.x * 256 + threadIdx.x;
  if (i >= total) return;
  float4 v = reinterpret_cast<const float4*>(x)[i];
  unsigned lo = (unsigned)f2bf(v.x) | ((unsigned)f2bf(v.y) << 16);
  unsigned hi = (unsigned)f2bf(v.z) | ((unsigned)f2bf(v.w) << 16);
  reinterpret_cast<uint2*>(dst)[i] = make_uint2(lo, hi);
}

// Btr[layer][r][c][k] bf16: r<8 -> W[r][k][c], r=8 -> SL[k][c]
__global__ __launch_bounds__(256) void wcvt(const float* __restrict__ W1,
                                            const float* __restrict__ SL1,
                                            const float* __restrict__ W2,
                                            const float* __restrict__ SL2,
                                            unsigned short* __restrict__ Btr) {
  int idx = blockIdx.x * 256 + threadIdx.x;
  if (idx >= 2 * 9 * D * D) return;
  int l = idx >= 9 * D * D;
  int t = idx - l * 9 * D * D;
  int r = t >> 14;
  int rem = t & 16383;
  int c = rem >> 7;
  int k = rem & 127;
  const float* W = l ? W2 : W1;
  const float* SL = l ? SL2 : SL1;
  float v = (r < NREL) ? W[((r * D) + k) * D + c] : SL[k * D + c];
  Btr[idx] = f2bf(v);
}

__global__ __launch_bounds__(256) void hist_kernel(const int* __restrict__ dst,
                                                   int* __restrict__ counts,
                                                   int E) {
  int e = blockIdx.x * 256 + threadIdx.x;
  if (e >= E) return;
  atomicAdd(&counts[dst[e]], 1);
}

__global__ __launch_bounds__(256) void scan1(const int* __restrict__ in,
                                             int* __restrict__ out,
                                             int* __restrict__ bsum) {
  __shared__ int tmp[256];
  int t = threadIdx.x;
  long base = (long)blockIdx.x * 1024 + t * 4;
  int v[4];
  int s = 0;
#pragma unroll
  for (int j = 0; j < 4; ++j) {
    v[j] = in[base + j];
    s += v[j];
  }
  tmp[t] = s;
  __syncthreads();
  for (int off = 1; off < 256; off <<= 1) {
    int x = (t >= off) ? tmp[t - off] : 0;
    __syncthreads();
    tmp[t] += x;
    __syncthreads();
  }
  int run = tmp[t] - s;
  if (t == 255) bsum[blockIdx.x] = tmp[255];
#pragma unroll
  for (int j = 0; j < 4; ++j) {
    out[base + j] = run;
    run += v[j];
  }
}

__global__ __launch_bounds__(1024) void scan_top(int* __restrict__ bsum, int nb) {
  __shared__ int tmp[1024];
  int t = threadIdx.x;
  int v = (t < nb) ? bsum[t] : 0;
  tmp[t] = v;
  __syncthreads();
  for (int off = 1; off < 1024; off <<= 1) {
    int x = (t >= off) ? tmp[t - off] : 0;
    __syncthreads();
    tmp[t] += x;
    __syncthreads();
  }
  if (t < nb) bsum[t] = tmp[t] - v;
}

__global__ __launch_bounds__(256) void scan_add(int* __restrict__ starts,
                                                int* __restrict__ cursor,
                                                const int* __restrict__ bsum) {
  long base = (long)blockIdx.x * 1024 + threadIdx.x * 4;
  int add = bsum[blockIdx.x];
#pragma unroll
  for (int j = 0; j < 4; ++j) {
    int v = starts[base + j] + add;
    starts[base + j] = v;
    cursor[base + j] = v;
  }
}

// esz[pos] = rel*N + src : Z-row index of the message, sorted by dst
__global__ __launch_bounds__(256) void reorder(const int* __restrict__ src,
                                               const int* __restrict__ dst,
                                               const int* __restrict__ rel,
                                               int* __restrict__ cursor,
                                               int* __restrict__ esz, int E,
                                               int N) {
  int e = blockIdx.x * 256 + threadIdx.x;
  if (e >= E) return;
  int pos = atomicAdd(&cursor[dst[e]], 1);
  esz[pos] = rel[e] * N + src[e];
}

// Z[r][n] = x[n] @ W[r0+r] for r=0..rc-1. Pure-register MFMA, no LDS/barriers.
// Z-row slot s (u32) packs bf16 cols ((s&3)*16 + (s>>2), +64): lane's 4
// np-results are contiguous -> one dwordx4 store per (m,q), full 256B lines.
__global__ __launch_bounds__(256) void zgemm(
    const unsigned short* __restrict__ xb,
    const unsigned short* __restrict__ Btr /* chunk base */,
    unsigned* __restrict__ Z2, int N, int rc) {
  const int lane = threadIdx.x & 63;
  const int wave = threadIdx.x >> 6;
  const int l15 = lane & 15, lq = lane >> 4;
  const int wrow = (blockIdx.x * 4 + wave) * 32;
  if (wrow >= N) return;

  short8 af[2][4];
#pragma unroll
  for (int m = 0; m < 2; ++m) {
    int grow = wrow + m * 16 + l15;
    if (grow >= N) grow = N - 1;
#pragma unroll
    for (int kq = 0; kq < 4; ++kq)
      af[m][kq] = *reinterpret_cast<const short8*>(xb + (size_t)grow * D +
                                                   kq * 32 + lq * 8);
  }

  for (int r = 0; r < rc; ++r) {
    f32x4 accA[4][2], accB[4][2];  // [np][m]
#pragma unroll
    for (int np = 0; np < 4; ++np)
#pragma unroll
      for (int m = 0; m < 2; ++m)
#pragma unroll
        for (int q = 0; q < 4; ++q) {
          accA[np][m][q] = 0.f;
          accB[np][m][q] = 0.f;
        }
#pragma unroll
    for (int np = 0; np < 4; ++np) {
      const int cA = np * 16 + l15;
      short8 ba[4], bb[4];
#pragma unroll
      for (int kq = 0; kq < 4; ++kq) {
        ba[kq] = *reinterpret_cast<const short8*>(
            Btr + ((size_t)r * D + cA) * D + kq * 32 + lq * 8);
        bb[kq] = *reinterpret_cast<const short8*>(
            Btr + ((size_t)r * D + cA + 64) * D + kq * 32 + lq * 8);
      }
#pragma unroll
      for (int m = 0; m < 2; ++m)
#pragma unroll
        for (int kq = 0; kq < 4; ++kq) {
          accA[np][m] = __builtin_amdgcn_mfma_f32_16x16x32_bf16(
              af[m][kq], ba[kq], accA[np][m], 0, 0, 0);
          accB[np][m] = __builtin_amdgcn_mfma_f32_16x16x32_bf16(
              af[m][kq], bb[kq], accB[np][m], 0, 0, 0);
        }
    }
    // stores: C layout col=np*16+l15, row=lq*4+q. Lane writes slots
    // l15*4 + np (np=0..3) = 16B at Z2[row*64 + l15*4].
#pragma unroll
    for (int m = 0; m < 2; ++m)
#pragma unroll
      for (int q = 0; q < 4; ++q) {
        int grow = wrow + m * 16 + lq * 4 + q;
        if (grow < N) {
          uint4 pk;
          pk.x = cvt_pk_bf16(accA[0][m][q], accB[0][m][q]);
          pk.y = cvt_pk_bf16(accA[1][m][q], accB[1][m][q]);
          pk.z = cvt_pk_bf16(accA[2][m][q], accB[2][m][q]);
          pk.w = cvt_pk_bf16(accA[3][m][q], accB[3][m][q]);
          *reinterpret_cast<uint4*>(Z2 + ((size_t)r * N + grow) * 64 +
                                    l15 * 4) = pk;
        }
      }
  }
}

// Segment-sum over the dst-sorted edge list, relation-chunked.
// Pass 0 (final=0): agg2[row] (packed bf16, Z slot format) = partial sum.
// Pass 1 (final=1): out = relu(agg2 + rels [lo,hi) + self + bias).
// One wave per row; lane j owns packed cols c0=(j&3)*16+(j>>2), c1=c0+64.
__global__ __launch_bounds__(256) void segsum(
    const unsigned* __restrict__ Z2, const int* __restrict__ esz,
    const int* __restrict__ starts, const float* __restrict__ bias,
    unsigned* __restrict__ agg2, unsigned short* __restrict__ xout_b,
    float* __restrict__ outf, int N, int lo, int hi, int selfOff, int final) {
  int row = blockIdx.x * 4 + (threadIdx.x >> 6);
  if (row >= N) return;
  int lane = threadIdx.x & 63;
  const int c0 = (lane & 3) * 16 + (lane >> 2);
  int s0 = starts[row], s1 = starts[row + 1];
  const int zlo = lo * N, zhi = hi * N;
  float a0 = 0.f, a1 = 0.f;
  for (int base = s0; base < s1; base += 8) {
    int zr[8];
    bool ok[8];
#pragma unroll
    for (int j = 0; j < 8; ++j) {
      int e = base + j;
      int z = (e < s1) ? esz[e] : -1;
      ok[j] = (z >= zlo) & (z < zhi);
      zr[j] = ok[j] ? (z - zlo) : 0;
    }
    unsigned v[8];
#pragma unroll
    for (int j = 0; j < 8; ++j) v[j] = Z2[(size_t)zr[j] * 64 + lane];
#pragma unroll
    for (int j = 0; j < 8; ++j)
      if (ok[j]) {
        a0 += __builtin_bit_cast(float, v[j] << 16);
        a1 += __builtin_bit_cast(float, v[j] & 0xffff0000u);
      }
  }
  if (final) {
    {  // self-loop row (Z slot format)
      unsigned v = Z2[((size_t)selfOff * N + row) * 64 + lane];
      a0 += __builtin_bit_cast(float, v << 16);
      a1 += __builtin_bit_cast(float, v & 0xffff0000u);
    }
    {  // carried partial (packed bf16, same slot)
      unsigned v = agg2[(size_t)row * 64 + lane];
      a0 += __builtin_bit_cast(float, v << 16);
      a1 += __builtin_bit_cast(float, v & 0xffff0000u);
    }
    a0 = fmaxf(a0 + bias[c0], 0.f);
    a1 = fmaxf(a1 + bias[c0 + 64], 0.f);
    if (outf) {
      outf[(size_t)row * D + c0] = a0;
      outf[(size_t)row * D + c0 + 64] = a1;
    } else {
      xout_b[(size_t)row * D + c0] = f2bf(a0);
      xout_b[(size_t)row * D + c0 + 64] = f2bf(a1);
    }
  } else {
    agg2[(size_t)row * 64 + lane] = cvt_pk_bf16(a0, a1);
  }
}

extern "C" void kernel_launch(void* const* d_in, const int* in_sizes, int n_in,
                              void* d_out, int out_size, void* d_ws, size_t ws_size,
                              hipStream_t stream) {
  const float* emb = (const float*)d_in[0];
  const float* W1 = (const float*)d_in[1];
  const float* SL1 = (const float*)d_in[2];
  const float* B1 = (const float*)d_in[3];
  const float* W2 = (const float*)d_in[4];
  const float* SL2 = (const float*)d_in[5];
  const float* B2 = (const float*)d_in[6];
  const int* eidx = (const int*)d_in[7];
  const int* etyp = (const int*)d_in[8];
  const int N = in_sizes[0] / D;
  const int E = in_sizes[8];
  const int* srcp = eidx;
  const int* dstp = eidx + E;
  float* outp = (float*)d_out;

  const int nb = (N + 1 + 1023) >> 10;
  const size_t npad = (size_t)nb << 10;

  // workspace layout (~199 MB; proven-safe bound ~231 MB)
  char* w = (char*)d_ws;
  unsigned* Z2 = (unsigned*)w;                           // RC0*N*64 u32 (128 MB)
  unsigned* agg2 = Z2 + (size_t)RC0 * N * 64;            // N*64 u32 (25.6 MB)
  unsigned short* xb = (unsigned short*)(agg2 + (size_t)N * 64);  // N*128 bf16
  unsigned short* Btr = xb + (size_t)N * D;              // 2*9*128*128 bf16
  int* counts = (int*)(Btr + 2 * 9 * D * D);             // npad ints
  int* starts = counts + npad;
  int* cursor = starts + npad;
  int* bsum = cursor + npad;                             // 1024 ints
  int* esz = bsum + 1024;                                // E ints

  const int eb = (E + 255) / 256;
  const int zg_blocks = (N + 127) / 128;  // 4 waves x 32 rows
  const int ss_blocks = (N + 3) / 4;

  // preprocessing (graph structure shared by both layers)
  hipMemsetAsync(counts, 0, npad * 4, stream);
  cvt_x<<<(int)(((long)N * 32 + 255) / 256), 256, 0, stream>>>(emb, xb,
                                                               (long)N * 32);
  wcvt<<<(2 * 9 * D * D + 255) / 256, 256, 0, stream>>>(W1, SL1, W2, SL2, Btr);
  hist_kernel<<<eb, 256, 0, stream>>>(dstp, counts, E);
  scan1<<<nb, 256, 0, stream>>>(counts, starts, bsum);
  scan_top<<<1, 1024, 0, stream>>>(bsum, nb);
  scan_add<<<nb, 256, 0, stream>>>(starts, cursor, bsum);
  reorder<<<eb, 256, 0, stream>>>(srcp, dstp, etyp, cursor, esz, E, N);

  auto layer = [&](const unsigned short* Bt, const float* bias,
                   unsigned short* ob, float* of) {
    // chunk 0: rels 0..4 -> agg2 (packed bf16)
    zgemm<<<zg_blocks, 256, 0, stream>>>(xb, Bt, Z2, N, RC0);
    segsum<<<ss_blocks, 256, 0, stream>>>(Z2, esz, starts, bias, agg2, nullptr,
                                          nullptr, N, 0, RC0, 0, 0);
    // chunk 1: rels 5..7 + self-loop(8) -> finalize
    zgemm<<<zg_blocks, 256, 0, stream>>>(xb, Bt + (size_t)RC0 * D * D, Z2, N,
                                         RC1);
    segsum<<<ss_blocks, 256, 0, stream>>>(Z2, esz, starts, bias, agg2, ob, of,
                                          N, RC0, NREL, NREL - RC0, 1);
  };

  layer(Btr, B1, xb, nullptr);                 // layer 1: xb -> xb (bf16)
  layer(Btr + 9 * D * D, B2, nullptr, outp);   // layer 2: xb -> outp (f32)
}